// Round 1
// baseline (344.942 us; speedup 1.0000x reference)
//
#include <hip/hip_runtime.h>
#include <hip/hip_bf16.h>

#define T_TOK 8192
#define DIN   4096
#define DOUT  4096
#define RANK  64
#define NAD   8
#define TS    32          // tokens per tile
#define MAXTILES 264      // sum ceil(count_a/TS) <= 256+7
#define TOTR  (NAD*RANK)  // 512

typedef __bf16 bf16x8 __attribute__((ext_vector_type(8)));
typedef __bf16 bf16x4 __attribute__((ext_vector_type(4)));
typedef float  f32x4  __attribute__((ext_vector_type(4)));

// ---- workspace layout (bytes) ----
#define WS_CURSORS 0         // 8 int
#define WS_NTILES  64        // 1 int
#define WS_FLAG    128       // 1 int (ids are int64?)
#define WS_TINFO   256       // MAXTILES*3 int
#define WS_PERM    4096      // 8192 int
#define WS_XA      0x10000   // 8192*64 bf16 (1 MB)
#define WS_ABF     0x110000  // 512*4096 bf16 (4 MB)
#define WS_BT      0x510000  // 4096*512 bf16 (4 MB)  -> end 0x910000

// ---------------- prep: histogram + offsets + tile table ----------------
__global__ __launch_bounds__(1024) void hist_prep(const int* __restrict__ ids,
    int* __restrict__ cursors, int* __restrict__ ntilesp,
    int* __restrict__ flagp, int* __restrict__ tinfo) {
  __shared__ int cnt[NAD];
  __shared__ int s_is64;
  int tid = threadIdx.x, lane = tid & 63;
  if (tid < NAD) cnt[tid] = 0;
  if (tid == 0) s_is64 = 1;
  __syncthreads();
  // int64 detection: values are 0..7, so if data is i64 every odd 32-bit word is 0
  int any = 0;
  for (int i = tid; i < T_TOK; i += 1024)
    if (i & 1) any |= ids[i];
  if (any) s_is64 = 0;
  __syncthreads();
  int is64 = s_is64;
  int loc[NAD];
#pragma unroll
  for (int a = 0; a < NAD; ++a) loc[a] = 0;
  for (int t = tid; t < T_TOK; t += 1024) {
    int id = (is64 ? ids[2 * t] : ids[t]) & 7;
#pragma unroll
    for (int a = 0; a < NAD; ++a) {
      unsigned long long m = __ballot(id == a);
      if (lane == 0) loc[a] += __popcll(m);
    }
  }
  if (lane == 0) {
#pragma unroll
    for (int a = 0; a < NAD; ++a) if (loc[a]) atomicAdd(&cnt[a], loc[a]);
  }
  __syncthreads();
  if (tid == 0) {
    *flagp = is64;
    int ofs = 0, nt = 0;
    for (int a = 0; a < NAD; ++a) {
      int c = cnt[a];
      cursors[a] = ofs;
      for (int t0 = 0; t0 < c; t0 += TS) {
        tinfo[nt * 3 + 0] = a;
        tinfo[nt * 3 + 1] = ofs + t0;
        tinfo[nt * 3 + 2] = (c - t0 < TS) ? (c - t0) : TS;
        ++nt;
      }
      ofs += c;
    }
    *ntilesp = nt;
  }
}

// ---------------- scatter tokens into per-adapter groups ----------------
__global__ __launch_bounds__(512) void scatter_k(const int* __restrict__ ids,
    const int* __restrict__ flagp, int* __restrict__ cursors, int* __restrict__ perm) {
  int t = blockIdx.x * 512 + threadIdx.x;
  int id = ((*flagp) ? ids[2 * t] : ids[t]) & 7;
  int pos = atomicAdd(&cursors[id], 1);
  perm[pos] = t;
}

// ---------------- A fp32 -> bf16 (row major) ----------------
__global__ __launch_bounds__(256) void conv_a(const float* __restrict__ A,
                                              __bf16* __restrict__ Abf) {
  int i = blockIdx.x * 256 + threadIdx.x;          // TOTR*DIN/4 elements
  float4 v = ((const float4*)A)[i];
  bf16x4 o = { (__bf16)v.x, (__bf16)v.y, (__bf16)v.z, (__bf16)v.w };
  ((bf16x4*)Abf)[i] = o;
}

// ---------------- B fp32 [512][4096] -> Bt bf16 [4096][512] ----------------
__global__ __launch_bounds__(256) void trans_b(const float* __restrict__ B,
                                               __bf16* __restrict__ Bt) {
  __shared__ float t[64][65];
  int rb = blockIdx.x, db = blockIdx.y;
  int tid = threadIdx.x;
  int c = tid & 63, q = tid >> 6;                  // q: 0..3
#pragma unroll
  for (int i = 0; i < 16; ++i) {
    int r = i * 4 + q;
    t[r][c] = B[(size_t)(rb * 64 + r) * DOUT + db * 64 + c];
  }
  __syncthreads();
#pragma unroll
  for (int i = 0; i < 16; ++i) {
    int d = i * 4 + q;
    Bt[(size_t)(db * 64 + d) * TOTR + rb * 64 + c] = (__bf16)t[c][d];
  }
}

// ---------------- stage 1: xa[32 tok][64 rank] = X * A_a^T ----------------
// block = 512 (8 waves): wave w -> token rowblock (w&1), rank colblock (w>>1)
__global__ __launch_bounds__(512) void stage1(const float* __restrict__ x,
    const __bf16* __restrict__ Abf, const int* __restrict__ tinfo,
    const int* __restrict__ ntilesp, const int* __restrict__ perm,
    __bf16* __restrict__ xa) {
  int b = blockIdx.x;
  if (b >= *ntilesp) return;
  int a = tinfo[b * 3], start = tinfo[b * 3 + 1], nv = tinfo[b * 3 + 2];
  int tid = threadIdx.x, lane = tid & 63, w = tid >> 6;
  int rb = w & 1, cb = w >> 1;
  int l16 = lane & 15, lq = lane >> 4;
  int trow = rb * 16 + l16;
  int tok = (trow < nv) ? perm[start + trow] : 0;
  const float*  xrow = x + (size_t)tok * DIN + lq * 8;
  const __bf16* arow = Abf + (size_t)(a * RANK + cb * 16 + l16) * DIN + lq * 8;
  f32x4 acc = {0.f, 0.f, 0.f, 0.f};
#pragma unroll 4
  for (int k0 = 0; k0 < DIN; k0 += 32) {
    float4 x0 = *(const float4*)(xrow + k0);
    float4 x1 = *(const float4*)(xrow + k0 + 4);
    bf16x8 af = { (__bf16)x0.x, (__bf16)x0.y, (__bf16)x0.z, (__bf16)x0.w,
                  (__bf16)x1.x, (__bf16)x1.y, (__bf16)x1.z, (__bf16)x1.w };
    bf16x8 bfr = *(const bf16x8*)(arow + k0);
    acc = __builtin_amdgcn_mfma_f32_16x16x32_bf16(af, bfr, acc, 0, 0, 0);
  }
#pragma unroll
  for (int j = 0; j < 4; ++j) {
    int tr = rb * 16 + lq * 4 + j;
    if (tr < nv) {
      int tk = perm[start + tr];
      xa[(size_t)tk * RANK + cb * 16 + l16] = (__bf16)acc[j];
    }
  }
}

// ---------------- stage 2: out[32 tok][256 d] = base + 2 * xa * B_a ----------------
// block = 512 (8 waves): wave w -> token rowblock (w&1), d-group (w>>1) of 4x16
__global__ __launch_bounds__(512) void stage2(const __bf16* __restrict__ xa,
    const __bf16* __restrict__ Bt, const float* __restrict__ base,
    const int* __restrict__ tinfo, const int* __restrict__ ntilesp,
    const int* __restrict__ perm, float* __restrict__ out) {
  int b = blockIdx.y;
  if (b >= *ntilesp) return;
  int a = tinfo[b * 3], start = tinfo[b * 3 + 1], nv = tinfo[b * 3 + 2];
  int tid = threadIdx.x, lane = tid & 63, w = tid >> 6;
  int tb = w & 1, dg = w >> 1;
  int l16 = lane & 15, lq = lane >> 4;
  int ta = tb * 16 + l16;
  int tok_a = (ta < nv) ? perm[start + ta] : 0;
  const __bf16* xrow = xa + (size_t)tok_a * RANK + lq * 8;
  bf16x8 af0 = *(const bf16x8*)(xrow);
  bf16x8 af1 = *(const bf16x8*)(xrow + 32);
  int dbase = blockIdx.x * 256 + dg * 64;
  int tk4[4];
#pragma unroll
  for (int j = 0; j < 4; ++j) {
    int tr = tb * 16 + lq * 4 + j;
    tk4[j] = (tr < nv) ? perm[start + tr] : -1;
  }
  f32x4 acc[4];
#pragma unroll
  for (int dt = 0; dt < 4; ++dt) {
    int d = dbase + dt * 16 + l16;
    const __bf16* brow = Bt + (size_t)d * TOTR + a * RANK + lq * 8;
    bf16x8 b0 = *(const bf16x8*)(brow);
    bf16x8 b1 = *(const bf16x8*)(brow + 32);
    f32x4 z = {0.f, 0.f, 0.f, 0.f};
    z = __builtin_amdgcn_mfma_f32_16x16x32_bf16(af0, b0, z, 0, 0, 0);
    z = __builtin_amdgcn_mfma_f32_16x16x32_bf16(af1, b1, z, 0, 0, 0);
    acc[dt] = z;
  }
#pragma unroll
  for (int dt = 0; dt < 4; ++dt) {
    int d = dbase + dt * 16 + l16;
#pragma unroll
    for (int j = 0; j < 4; ++j) {
      if (tk4[j] >= 0) {
        size_t o = (size_t)tk4[j] * DOUT + d;
        out[o] = base[o] + 2.0f * acc[dt][j];
      }
    }
  }
}

extern "C" void kernel_launch(void* const* d_in, const int* in_sizes, int n_in,
                              void* d_out, int out_size, void* d_ws, size_t ws_size,
                              hipStream_t stream) {
  const float* x   = (const float*)d_in[0];
  const float* A   = (const float*)d_in[1];
  const float* B   = (const float*)d_in[2];
  const float* bas = (const float*)d_in[3];
  const int*   ids = (const int*)d_in[4];
  float* out = (float*)d_out;
  char* ws = (char*)d_ws;
  int* cursors = (int*)(ws + WS_CURSORS);
  int* ntiles  = (int*)(ws + WS_NTILES);
  int* flag    = (int*)(ws + WS_FLAG);
  int* tinfo   = (int*)(ws + WS_TINFO);
  int* perm    = (int*)(ws + WS_PERM);
  __bf16* xa   = (__bf16*)(ws + WS_XA);
  __bf16* Abf  = (__bf16*)(ws + WS_ABF);
  __bf16* Bt   = (__bf16*)(ws + WS_BT);

  hist_prep<<<1, 1024, 0, stream>>>(ids, cursors, ntiles, flag, tinfo);
  scatter_k<<<T_TOK / 512, 512, 0, stream>>>(ids, flag, cursors, perm);
  conv_a<<<(TOTR * DIN / 4) / 256, 256, 0, stream>>>(A, Abf);
  trans_b<<<dim3(TOTR / 64, DOUT / 64), 256, 0, stream>>>(B, Bt);
  stage1<<<MAXTILES, 512, 0, stream>>>(x, Abf, tinfo, ntiles, perm, xa);
  stage2<<<dim3(DOUT / 256, MAXTILES), 512, 0, stream>>>(xa, Bt, bas, tinfo, ntiles, perm, out);
}

// Round 2
// 262.739 us; speedup vs baseline: 1.3129x; 1.3129x over previous
//
#include <hip/hip_runtime.h>
#include <hip/hip_bf16.h>

#define T_TOK 8192
#define DIN   4096
#define DOUT  4096
#define RANK  64
#define NAD   8
#define TS    32          // tokens per tile
#define MAXTILES 264      // sum ceil(count_a/TS) <= 256+7
#define TOTR  (NAD*RANK)  // 512
#define KSPLIT 4
#define KCH   (DIN / KSPLIT)   // 1024

typedef __bf16 bf16x8 __attribute__((ext_vector_type(8)));
typedef __bf16 bf16x4 __attribute__((ext_vector_type(4)));
typedef float  f32x4  __attribute__((ext_vector_type(4)));

// ---- workspace layout (bytes) ----
#define WS_CURSORS 0         // 8 int
#define WS_NTILES  64        // 1 int
#define WS_FLAG    128       // 1 int (ids are int64?)
#define WS_TINFO   256       // MAXTILES*3 int
#define WS_PERM    4096      // 8192 int
#define WS_XA      0x10000   // 8192*64 bf16 (1 MB)
#define WS_ABF     0x110000  // 512*4096 bf16 (4 MB)
#define WS_BT      0x510000  // 4096*512 bf16 (4 MB)
#define WS_XAP     0x910000  // KSPLIT*8192*64 fp32 (8 MB)
#define WS_END     (0x910000 + (size_t)KSPLIT * T_TOK * RANK * 4)

// ---------------- prep: histogram + offsets + tile table ----------------
__global__ __launch_bounds__(1024) void hist_prep(const int* __restrict__ ids,
    int* __restrict__ cursors, int* __restrict__ ntilesp,
    int* __restrict__ flagp, int* __restrict__ tinfo) {
  __shared__ int cnt[NAD];
  __shared__ int s_is64;
  int tid = threadIdx.x, lane = tid & 63;
  if (tid < NAD) cnt[tid] = 0;
  if (tid == 0) s_is64 = 1;
  __syncthreads();
  // int64 detection: values are 0..7, so if data is i64 every odd 32-bit word is 0
  int any = 0;
  for (int i = tid; i < T_TOK; i += 1024)
    if (i & 1) any |= ids[i];
  if (any) s_is64 = 0;
  __syncthreads();
  int is64 = s_is64;
  int loc[NAD];
#pragma unroll
  for (int a = 0; a < NAD; ++a) loc[a] = 0;
  for (int t = tid; t < T_TOK; t += 1024) {
    int id = (is64 ? ids[2 * t] : ids[t]) & 7;
#pragma unroll
    for (int a = 0; a < NAD; ++a) {
      unsigned long long m = __ballot(id == a);
      if (lane == 0) loc[a] += __popcll(m);
    }
  }
  if (lane == 0) {
#pragma unroll
    for (int a = 0; a < NAD; ++a) if (loc[a]) atomicAdd(&cnt[a], loc[a]);
  }
  __syncthreads();
  if (tid == 0) {
    *flagp = is64;
    int ofs = 0, nt = 0;
    for (int a = 0; a < NAD; ++a) {
      int c = cnt[a];
      cursors[a] = ofs;
      for (int t0 = 0; t0 < c; t0 += TS) {
        tinfo[nt * 3 + 0] = a;
        tinfo[nt * 3 + 1] = ofs + t0;
        tinfo[nt * 3 + 2] = (c - t0 < TS) ? (c - t0) : TS;
        ++nt;
      }
      ofs += c;
    }
    *ntilesp = nt;
  }
}

// ---------------- scatter tokens into per-adapter groups ----------------
__global__ __launch_bounds__(512) void scatter_k(const int* __restrict__ ids,
    const int* __restrict__ flagp, int* __restrict__ cursors, int* __restrict__ perm) {
  int t = blockIdx.x * 512 + threadIdx.x;
  int id = ((*flagp) ? ids[2 * t] : ids[t]) & 7;
  int pos = atomicAdd(&cursors[id], 1);
  perm[pos] = t;
}

// ---------------- A fp32 -> bf16 (row major) ----------------
__global__ __launch_bounds__(256) void conv_a(const float* __restrict__ A,
                                              __bf16* __restrict__ Abf) {
  int i = blockIdx.x * 256 + threadIdx.x;          // TOTR*DIN/4 elements
  float4 v = ((const float4*)A)[i];
  bf16x4 o = { (__bf16)v.x, (__bf16)v.y, (__bf16)v.z, (__bf16)v.w };
  ((bf16x4*)Abf)[i] = o;
}

// ---------------- B fp32 [512][4096] -> Bt bf16 [4096][512] ----------------
__global__ __launch_bounds__(256) void trans_b(const float* __restrict__ B,
                                               __bf16* __restrict__ Bt) {
  __shared__ float t[64][65];
  int rb = blockIdx.x, db = blockIdx.y;
  int tid = threadIdx.x;
  int c = tid & 63, q = tid >> 6;                  // q: 0..3
#pragma unroll
  for (int i = 0; i < 16; ++i) {
    int r = i * 4 + q;
    t[r][c] = B[(size_t)(rb * 64 + r) * DOUT + db * 64 + c];
  }
  __syncthreads();
#pragma unroll
  for (int i = 0; i < 16; ++i) {
    int d = i * 4 + q;
    Bt[(size_t)(db * 64 + d) * TOTR + rb * 64 + c] = (__bf16)t[c][d];
  }
}

#define CVT8(lo, hi) { (__bf16)lo.x, (__bf16)lo.y, (__bf16)lo.z, (__bf16)lo.w, \
                       (__bf16)hi.x, (__bf16)hi.y, (__bf16)hi.z, (__bf16)hi.w }

// ---------------- stage 1 (split-K): xap[ks][tok][rank] partial = X * A_a^T ----------------
// grid (MAXTILES, KSPLIT), block 512 (8 waves): wave -> token half (w&1), rank quarter (w>>1)
__global__ __launch_bounds__(512, 4) void stage1s(const float* __restrict__ x,
    const __bf16* __restrict__ Abf, const int* __restrict__ tinfo,
    const int* __restrict__ ntilesp, const int* __restrict__ perm,
    float* __restrict__ xap) {
  int b = blockIdx.x;
  if (b >= *ntilesp) return;
  int ks = blockIdx.y;
  int a = tinfo[b * 3], start = tinfo[b * 3 + 1], nv = tinfo[b * 3 + 2];
  int tid = threadIdx.x, lane = tid & 63, w = tid >> 6;
  int rb = w & 1, cb = w >> 1;
  int l16 = lane & 15, lq = lane >> 4;
  int trow = rb * 16 + l16;
  int tok = (trow < nv) ? perm[start + trow] : 0;
  const float*  xr = x + (size_t)tok * DIN + ks * KCH + lq * 8;
  const __bf16* ar = Abf + (size_t)(a * RANK + cb * 16 + l16) * DIN + ks * KCH + lq * 8;
  f32x4 acc = {0.f, 0.f, 0.f, 0.f};
  // software pipeline over 16 chunks of K=64 (2 MFMAs each)
  float4 x0 = *(const float4*)(xr);
  float4 x1 = *(const float4*)(xr + 4);
  float4 x2 = *(const float4*)(xr + 32);
  float4 x3 = *(const float4*)(xr + 36);
  bf16x8 a0 = *(const bf16x8*)(ar);
  bf16x8 a1 = *(const bf16x8*)(ar + 32);
#pragma unroll
  for (int c = 0; c < KCH / 64 - 1; ++c) {
    const float*  xp = xr + (c + 1) * 64;
    const __bf16* ap = ar + (c + 1) * 64;
    float4 nx0 = *(const float4*)(xp);
    float4 nx1 = *(const float4*)(xp + 4);
    float4 nx2 = *(const float4*)(xp + 32);
    float4 nx3 = *(const float4*)(xp + 36);
    bf16x8 na0 = *(const bf16x8*)(ap);
    bf16x8 na1 = *(const bf16x8*)(ap + 32);
    bf16x8 af0 = CVT8(x0, x1);
    acc = __builtin_amdgcn_mfma_f32_16x16x32_bf16(af0, a0, acc, 0, 0, 0);
    bf16x8 af1 = CVT8(x2, x3);
    acc = __builtin_amdgcn_mfma_f32_16x16x32_bf16(af1, a1, acc, 0, 0, 0);
    x0 = nx0; x1 = nx1; x2 = nx2; x3 = nx3; a0 = na0; a1 = na1;
  }
  {
    bf16x8 af0 = CVT8(x0, x1);
    acc = __builtin_amdgcn_mfma_f32_16x16x32_bf16(af0, a0, acc, 0, 0, 0);
    bf16x8 af1 = CVT8(x2, x3);
    acc = __builtin_amdgcn_mfma_f32_16x16x32_bf16(af1, a1, acc, 0, 0, 0);
  }
  float* xo = xap + (size_t)ks * T_TOK * RANK;
#pragma unroll
  for (int j = 0; j < 4; ++j) {
    int tr = rb * 16 + lq * 4 + j;
    if (tr < nv) {
      int tk = perm[start + tr];
      xo[(size_t)tk * RANK + cb * 16 + l16] = acc[j];
    }
  }
}

// ---------------- reduce partials -> bf16 xa ----------------
__global__ __launch_bounds__(256) void reduce_xa(const float* __restrict__ xap,
                                                 __bf16* __restrict__ xa) {
  int i = blockIdx.x * 256 + threadIdx.x;          // 131072 float4 groups
  const float4* p = (const float4*)xap;
  float4 s = p[i];
#pragma unroll
  for (int ks = 1; ks < KSPLIT; ++ks) {
    float4 q = p[(size_t)ks * (T_TOK * RANK / 4) + i];
    s.x += q.x; s.y += q.y; s.z += q.z; s.w += q.w;
  }
  bf16x4 o = { (__bf16)s.x, (__bf16)s.y, (__bf16)s.z, (__bf16)s.w };
  ((bf16x4*)xa)[i] = o;
}

// ---------------- stage 1 fallback (no split-K) — used only if ws too small ----------------
__global__ __launch_bounds__(512) void stage1f(const float* __restrict__ x,
    const __bf16* __restrict__ Abf, const int* __restrict__ tinfo,
    const int* __restrict__ ntilesp, const int* __restrict__ perm,
    __bf16* __restrict__ xa) {
  int b = blockIdx.x;
  if (b >= *ntilesp) return;
  int a = tinfo[b * 3], start = tinfo[b * 3 + 1], nv = tinfo[b * 3 + 2];
  int tid = threadIdx.x, lane = tid & 63, w = tid >> 6;
  int rb = w & 1, cb = w >> 1;
  int l16 = lane & 15, lq = lane >> 4;
  int trow = rb * 16 + l16;
  int tok = (trow < nv) ? perm[start + trow] : 0;
  const float*  xrow = x + (size_t)tok * DIN + lq * 8;
  const __bf16* arow = Abf + (size_t)(a * RANK + cb * 16 + l16) * DIN + lq * 8;
  f32x4 acc = {0.f, 0.f, 0.f, 0.f};
#pragma unroll 4
  for (int k0 = 0; k0 < DIN; k0 += 32) {
    float4 v0 = *(const float4*)(xrow + k0);
    float4 v1 = *(const float4*)(xrow + k0 + 4);
    bf16x8 af = CVT8(v0, v1);
    bf16x8 bfr = *(const bf16x8*)(arow + k0);
    acc = __builtin_amdgcn_mfma_f32_16x16x32_bf16(af, bfr, acc, 0, 0, 0);
  }
#pragma unroll
  for (int j = 0; j < 4; ++j) {
    int tr = rb * 16 + lq * 4 + j;
    if (tr < nv) {
      int tk = perm[start + tr];
      xa[(size_t)tk * RANK + cb * 16 + l16] = (__bf16)acc[j];
    }
  }
}

// ---------------- stage 2: out[32 tok][128 d] = base + 2 * xa * B_a ----------------
// grid (DOUT/128, MAXTILES), block 512 (8 waves): wave -> token half (w&1), d-group (w>>1) of 2x16
__global__ __launch_bounds__(512, 4) void stage2(const __bf16* __restrict__ xa,
    const __bf16* __restrict__ Bt, const float* __restrict__ base,
    const int* __restrict__ tinfo, const int* __restrict__ ntilesp,
    const int* __restrict__ perm, float* __restrict__ out) {
  int b = blockIdx.y;
  if (b >= *ntilesp) return;
  int a = tinfo[b * 3], start = tinfo[b * 3 + 1], nv = tinfo[b * 3 + 2];
  int tid = threadIdx.x, lane = tid & 63, w = tid >> 6;
  int tb = w & 1, dg = w >> 1;
  int l16 = lane & 15, lq = lane >> 4;
  int ta = tb * 16 + l16;
  int tok_a = (ta < nv) ? perm[start + ta] : 0;
  const __bf16* xrow = xa + (size_t)tok_a * RANK + lq * 8;
  bf16x8 af0 = *(const bf16x8*)(xrow);
  bf16x8 af1 = *(const bf16x8*)(xrow + 32);
  int dbase = blockIdx.x * 128 + dg * 32;
  int tk4[4];
#pragma unroll
  for (int j = 0; j < 4; ++j) {
    int tr = tb * 16 + lq * 4 + j;
    tk4[j] = (tr < nv) ? perm[start + tr] : -1;
  }
  // hoist all Bt loads (2 d-tiles x K=64)
  int d0 = dbase + l16, d1 = dbase + 16 + l16;
  const __bf16* br0 = Bt + (size_t)d0 * TOTR + a * RANK + lq * 8;
  const __bf16* br1 = Bt + (size_t)d1 * TOTR + a * RANK + lq * 8;
  bf16x8 b00 = *(const bf16x8*)(br0);
  bf16x8 b01 = *(const bf16x8*)(br0 + 32);
  bf16x8 b10 = *(const bf16x8*)(br1);
  bf16x8 b11 = *(const bf16x8*)(br1 + 32);
  // hoist base loads
  float bs[2][4];
#pragma unroll
  for (int j = 0; j < 4; ++j) {
    bs[0][j] = (tk4[j] >= 0) ? base[(size_t)tk4[j] * DOUT + d0] : 0.f;
    bs[1][j] = (tk4[j] >= 0) ? base[(size_t)tk4[j] * DOUT + d1] : 0.f;
  }
  f32x4 z0 = {0.f, 0.f, 0.f, 0.f}, z1 = {0.f, 0.f, 0.f, 0.f};
  z0 = __builtin_amdgcn_mfma_f32_16x16x32_bf16(af0, b00, z0, 0, 0, 0);
  z0 = __builtin_amdgcn_mfma_f32_16x16x32_bf16(af1, b01, z0, 0, 0, 0);
  z1 = __builtin_amdgcn_mfma_f32_16x16x32_bf16(af0, b10, z1, 0, 0, 0);
  z1 = __builtin_amdgcn_mfma_f32_16x16x32_bf16(af1, b11, z1, 0, 0, 0);
#pragma unroll
  for (int j = 0; j < 4; ++j) {
    if (tk4[j] >= 0) {
      size_t o0 = (size_t)tk4[j] * DOUT + d0;
      size_t o1 = (size_t)tk4[j] * DOUT + d1;
      out[o0] = bs[0][j] + 2.0f * z0[j];
      out[o1] = bs[1][j] + 2.0f * z1[j];
    }
  }
}

extern "C" void kernel_launch(void* const* d_in, const int* in_sizes, int n_in,
                              void* d_out, int out_size, void* d_ws, size_t ws_size,
                              hipStream_t stream) {
  const float* x   = (const float*)d_in[0];
  const float* A   = (const float*)d_in[1];
  const float* B   = (const float*)d_in[2];
  const float* bas = (const float*)d_in[3];
  const int*   ids = (const int*)d_in[4];
  float* out = (float*)d_out;
  char* ws = (char*)d_ws;
  int* cursors = (int*)(ws + WS_CURSORS);
  int* ntiles  = (int*)(ws + WS_NTILES);
  int* flag    = (int*)(ws + WS_FLAG);
  int* tinfo   = (int*)(ws + WS_TINFO);
  int* perm    = (int*)(ws + WS_PERM);
  __bf16* xa   = (__bf16*)(ws + WS_XA);
  __bf16* Abf  = (__bf16*)(ws + WS_ABF);
  __bf16* Bt   = (__bf16*)(ws + WS_BT);
  float*  xap  = (float*)(ws + WS_XAP);

  hist_prep<<<1, 1024, 0, stream>>>(ids, cursors, ntiles, flag, tinfo);
  scatter_k<<<T_TOK / 512, 512, 0, stream>>>(ids, flag, cursors, perm);
  conv_a<<<(TOTR * DIN / 4) / 256, 256, 0, stream>>>(A, Abf);
  trans_b<<<dim3(TOTR / 64, DOUT / 64), 256, 0, stream>>>(B, Bt);
  if (ws_size >= WS_END) {
    stage1s<<<dim3(MAXTILES, KSPLIT), 512, 0, stream>>>(x, Abf, tinfo, ntiles, perm, xap);
    reduce_xa<<<(T_TOK * RANK / 4) / 256, 256, 0, stream>>>(xap, xa);
  } else {
    stage1f<<<MAXTILES, 512, 0, stream>>>(x, Abf, tinfo, ntiles, perm, xa);
  }
  stage2<<<dim3(DOUT / 128, MAXTILES), 512, 0, stream>>>(xa, Bt, bas, tinfo, ntiles, perm, out);
}

// Round 3
// 196.321 us; speedup vs baseline: 1.7570x; 1.3383x over previous
//
#include <hip/hip_runtime.h>
#include <hip/hip_bf16.h>

#define T_TOK 8192
#define DIN   4096
#define DOUT  4096
#define RANK  64
#define NAD   8
#define TS    32          // tokens per tile
#define MAXTILES 264      // sum ceil(count_a/TS) <= 256+7
#define TOTR  (NAD*RANK)  // 512
#define KSPLIT 4
#define KCH   (DIN / KSPLIT)   // 1024
#define NT    (KCH / 64)       // 16 K-steps of BK=64

typedef __bf16 bf16x8 __attribute__((ext_vector_type(8)));
typedef __bf16 bf16x4 __attribute__((ext_vector_type(4)));
typedef float  f32x4  __attribute__((ext_vector_type(4)));

// ---- workspace layout (bytes) ----
#define WS_CURSORS 0         // 8 int
#define WS_NTILES  64        // 1 int
#define WS_FLAG    128       // 1 int (ids are int64?)
#define WS_TINFO   256       // MAXTILES*3 int
#define WS_PERM    4096      // 8192 int
#define WS_XA      0x10000   // 8192*64 bf16 (1 MB)
#define WS_ABF     0x110000  // 512*4096 bf16 (4 MB)
#define WS_BT      0x510000  // 4096*512 bf16 (4 MB)
#define WS_XAP     0x910000  // KSPLIT*8192*64 fp32 (8 MB)
#define WS_END     (0x910000 + (size_t)KSPLIT * T_TOK * RANK * 4)

__device__ __forceinline__ void gll16(const void* g, void* l) {
  __builtin_amdgcn_global_load_lds(
      (const __attribute__((address_space(1))) unsigned int*)g,
      (__attribute__((address_space(3))) unsigned int*)l, 16, 0, 0);
}

// ---------------- prep: histogram + offsets + tile table ----------------
__global__ __launch_bounds__(1024) void hist_prep(const int* __restrict__ ids,
    int* __restrict__ cursors, int* __restrict__ ntilesp,
    int* __restrict__ flagp, int* __restrict__ tinfo) {
  __shared__ int cnt[NAD];
  __shared__ int s_is64;
  int tid = threadIdx.x, lane = tid & 63;
  if (tid < NAD) cnt[tid] = 0;
  if (tid == 0) s_is64 = 1;
  __syncthreads();
  // int64 detection: values are 0..7, so if data is i64 every odd 32-bit word is 0
  int any = 0;
  for (int i = tid; i < T_TOK; i += 1024)
    if (i & 1) any |= ids[i];
  if (any) s_is64 = 0;
  __syncthreads();
  int is64 = s_is64;
  int loc[NAD];
#pragma unroll
  for (int a = 0; a < NAD; ++a) loc[a] = 0;
  for (int t = tid; t < T_TOK; t += 1024) {
    int id = (is64 ? ids[2 * t] : ids[t]) & 7;
#pragma unroll
    for (int a = 0; a < NAD; ++a) {
      unsigned long long m = __ballot(id == a);
      if (lane == 0) loc[a] += __popcll(m);
    }
  }
  if (lane == 0) {
#pragma unroll
    for (int a = 0; a < NAD; ++a) if (loc[a]) atomicAdd(&cnt[a], loc[a]);
  }
  __syncthreads();
  if (tid == 0) {
    *flagp = is64;
    int ofs = 0, nt = 0;
    for (int a = 0; a < NAD; ++a) {
      int c = cnt[a];
      cursors[a] = ofs;
      for (int t0 = 0; t0 < c; t0 += TS) {
        tinfo[nt * 3 + 0] = a;
        tinfo[nt * 3 + 1] = ofs + t0;
        tinfo[nt * 3 + 2] = (c - t0 < TS) ? (c - t0) : TS;
        ++nt;
      }
      ofs += c;
    }
    *ntilesp = nt;
  }
}

// ---------------- scatter tokens into per-adapter groups ----------------
__global__ __launch_bounds__(512) void scatter_k(const int* __restrict__ ids,
    const int* __restrict__ flagp, int* __restrict__ cursors, int* __restrict__ perm) {
  int t = blockIdx.x * 512 + threadIdx.x;
  int id = ((*flagp) ? ids[2 * t] : ids[t]) & 7;
  int pos = atomicAdd(&cursors[id], 1);
  perm[pos] = t;
}

// ---------------- A fp32 -> bf16 (row major) ----------------
__global__ __launch_bounds__(256) void conv_a(const float* __restrict__ A,
                                              __bf16* __restrict__ Abf) {
  int i = blockIdx.x * 256 + threadIdx.x;          // TOTR*DIN/4 elements
  float4 v = ((const float4*)A)[i];
  bf16x4 o = { (__bf16)v.x, (__bf16)v.y, (__bf16)v.z, (__bf16)v.w };
  ((bf16x4*)Abf)[i] = o;
}

// ---------------- B fp32 [512][4096] -> Bt bf16 [4096][512] ----------------
__global__ __launch_bounds__(256) void trans_b(const float* __restrict__ B,
                                               __bf16* __restrict__ Bt) {
  __shared__ float t[64][65];
  int rb = blockIdx.x, db = blockIdx.y;
  int tid = threadIdx.x;
  int c = tid & 63, q = tid >> 6;                  // q: 0..3
#pragma unroll
  for (int i = 0; i < 16; ++i) {
    int r = i * 4 + q;
    t[r][c] = B[(size_t)(rb * 64 + r) * DOUT + db * 64 + c];
  }
  __syncthreads();
#pragma unroll
  for (int i = 0; i < 16; ++i) {
    int d = i * 4 + q;
    Bt[(size_t)(db * 64 + d) * TOTR + rb * 64 + c] = (__bf16)t[c][d];
  }
}

#define CVT8(lo, hi) { (__bf16)lo.x, (__bf16)lo.y, (__bf16)lo.z, (__bf16)lo.w, \
                       (__bf16)hi.x, (__bf16)hi.y, (__bf16)hi.z, (__bf16)hi.w }

// ---------------- stage 1 (split-K, LDS-staged): xap[ks][tok][rank] = X * A_a^T ----------------
// grid (MAXTILES, KSPLIT), block 512 (8 waves).
// Per K-step (BK=64): stage x-tile [32 tok][64 K] fp32 (8KB) + A-tile [64 r][64 K] bf16 (8KB)
// via global_load_lds (1KB per wave per tile), double-buffered, counted vmcnt(2).
// LDS layout linear; bank-conflict fix = XOR swizzle ((row&7)<<4) applied on the GLOBAL
// source inner offset AND the LDS read address (both-sides rule).
__global__ __launch_bounds__(512) void stage1s(const float* __restrict__ x,
    const __bf16* __restrict__ Abf, const int* __restrict__ tinfo,
    const int* __restrict__ ntilesp, const int* __restrict__ perm,
    float* __restrict__ xap) {
  __shared__ char lds[2][16384];   // per buf: [0,8192) = x tile, [8192,16384) = A tile
  int b = blockIdx.x;
  if (b >= *ntilesp) return;       // uniform
  int ks = blockIdx.y;
  int a = tinfo[b * 3], start = tinfo[b * 3 + 1], nv = tinfo[b * 3 + 2];
  int tid = threadIdx.x, lane = tid & 63, wv = tid >> 6;

  // ---- staging addresses (constant across K-steps) ----
  int xr = wv * 4 + (lane >> 4);                       // x row this lane stages
  int xtok = (xr < nv) ? perm[start + xr] : perm[start];
  int xinner = ((lane & 15) * 16) ^ ((xr & 7) << 4);   // swizzled source inner bytes
  const char* xsrc = (const char*)(x + (size_t)xtok * DIN + ks * KCH) + xinner;
  int ar = wv * 8 + (lane >> 3);                       // A row this lane stages
  int ainner = ((lane & 7) * 16) ^ ((ar & 7) << 4);
  const char* asrc = (const char*)(Abf + (size_t)(a * RANK + ar) * DIN + ks * KCH) + ainner;

  // ---- compute-side indices ----
  int l16 = lane & 15, lq = lane >> 4;
  int rb = wv & 1, cb = wv >> 1;
  int xrow = rb * 16 + l16;        // token row (MFMA A-operand)
  int arow = cb * 16 + l16;        // rank row  (MFMA B-operand)
  int swx = (xrow & 7) << 4;
  int swa = (arow & 7) << 4;

  f32x4 acc = {0.f, 0.f, 0.f, 0.f};

  // prologue: stage K-step 0 into buf 0
  gll16(xsrc, &lds[0][wv * 1024]);
  gll16(asrc, &lds[0][8192 + wv * 1024]);

  for (int t = 0; t < NT; ++t) {
    const char* cbuf = lds[t & 1];
    if (t + 1 < NT) {
      char* nbuf = lds[(t + 1) & 1];
      gll16(xsrc + (size_t)(t + 1) * 256, nbuf + wv * 1024);
      gll16(asrc + (size_t)(t + 1) * 128, nbuf + 8192 + wv * 1024);
      asm volatile("s_waitcnt vmcnt(2)" ::: "memory");   // cur's 2 loads landed
    } else {
      asm volatile("s_waitcnt vmcnt(0)" ::: "memory");
    }
    __builtin_amdgcn_s_barrier();
    asm volatile("" ::: "memory");
#pragma unroll
    for (int m = 0; m < 2; ++m) {
      f32x4 xv0 = *(const f32x4*)(cbuf + xrow * 256 + ((m * 128 + lq * 32) ^ swx));
      f32x4 xv1 = *(const f32x4*)(cbuf + xrow * 256 + ((m * 128 + lq * 32 + 16) ^ swx));
      bf16x8 xf = { (__bf16)xv0[0], (__bf16)xv0[1], (__bf16)xv0[2], (__bf16)xv0[3],
                    (__bf16)xv1[0], (__bf16)xv1[1], (__bf16)xv1[2], (__bf16)xv1[3] };
      bf16x8 af = *(const bf16x8*)(cbuf + 8192 + arow * 128 + ((m * 64 + lq * 16) ^ swa));
      acc = __builtin_amdgcn_mfma_f32_16x16x32_bf16(xf, af, acc, 0, 0, 0);
    }
    asm volatile("" ::: "memory");
    __builtin_amdgcn_s_barrier();
  }

  float* xo = xap + (size_t)ks * T_TOK * RANK;
#pragma unroll
  for (int j = 0; j < 4; ++j) {
    int tr = rb * 16 + lq * 4 + j;
    if (tr < nv) {
      int tk = perm[start + tr];
      xo[(size_t)tk * RANK + cb * 16 + l16] = acc[j];
    }
  }
}

// ---------------- reduce partials -> bf16 xa ----------------
__global__ __launch_bounds__(256) void reduce_xa(const float* __restrict__ xap,
                                                 __bf16* __restrict__ xa) {
  int i = blockIdx.x * 256 + threadIdx.x;          // 131072 float4 groups
  const float4* p = (const float4*)xap;
  float4 s = p[i];
#pragma unroll
  for (int ks = 1; ks < KSPLIT; ++ks) {
    float4 q = p[(size_t)ks * (T_TOK * RANK / 4) + i];
    s.x += q.x; s.y += q.y; s.z += q.z; s.w += q.w;
  }
  bf16x4 o = { (__bf16)s.x, (__bf16)s.y, (__bf16)s.z, (__bf16)s.w };
  ((bf16x4*)xa)[i] = o;
}

// ---------------- stage 1 fallback (no split-K) — used only if ws too small ----------------
__global__ __launch_bounds__(512) void stage1f(const float* __restrict__ x,
    const __bf16* __restrict__ Abf, const int* __restrict__ tinfo,
    const int* __restrict__ ntilesp, const int* __restrict__ perm,
    __bf16* __restrict__ xa) {
  int b = blockIdx.x;
  if (b >= *ntilesp) return;
  int a = tinfo[b * 3], start = tinfo[b * 3 + 1], nv = tinfo[b * 3 + 2];
  int tid = threadIdx.x, lane = tid & 63, w = tid >> 6;
  int rb = w & 1, cb = w >> 1;
  int l16 = lane & 15, lq = lane >> 4;
  int trow = rb * 16 + l16;
  int tok = (trow < nv) ? perm[start + trow] : 0;
  const float*  xrow = x + (size_t)tok * DIN + lq * 8;
  const __bf16* arow = Abf + (size_t)(a * RANK + cb * 16 + l16) * DIN + lq * 8;
  f32x4 acc = {0.f, 0.f, 0.f, 0.f};
#pragma unroll 4
  for (int k0 = 0; k0 < DIN; k0 += 32) {
    float4 v0 = *(const float4*)(xrow + k0);
    float4 v1 = *(const float4*)(xrow + k0 + 4);
    bf16x8 af = CVT8(v0, v1);
    bf16x8 bfr = *(const bf16x8*)(arow + k0);
    acc = __builtin_amdgcn_mfma_f32_16x16x32_bf16(af, bfr, acc, 0, 0, 0);
  }
#pragma unroll
  for (int j = 0; j < 4; ++j) {
    int tr = rb * 16 + lq * 4 + j;
    if (tr < nv) {
      int tk = perm[start + tr];
      xa[(size_t)tk * RANK + cb * 16 + l16] = (__bf16)acc[j];
    }
  }
}

// ---------------- stage 2: out[32 tok][128 d] = base + 2 * xa * B_a ----------------
// grid (DOUT/128, MAXTILES), block 512 (8 waves): wave -> token half (w&1), d-group (w>>1) of 2x16
__global__ __launch_bounds__(512, 4) void stage2(const __bf16* __restrict__ xa,
    const __bf16* __restrict__ Bt, const float* __restrict__ base,
    const int* __restrict__ tinfo, const int* __restrict__ ntilesp,
    const int* __restrict__ perm, float* __restrict__ out) {
  int b = blockIdx.y;
  if (b >= *ntilesp) return;
  int a = tinfo[b * 3], start = tinfo[b * 3 + 1], nv = tinfo[b * 3 + 2];
  int tid = threadIdx.x, lane = tid & 63, w = tid >> 6;
  int tb = w & 1, dg = w >> 1;
  int l16 = lane & 15, lq = lane >> 4;
  int ta = tb * 16 + l16;
  int tok_a = (ta < nv) ? perm[start + ta] : 0;
  const __bf16* xrow = xa + (size_t)tok_a * RANK + lq * 8;
  bf16x8 af0 = *(const bf16x8*)(xrow);
  bf16x8 af1 = *(const bf16x8*)(xrow + 32);
  int dbase = blockIdx.x * 128 + dg * 32;
  int tk4[4];
#pragma unroll
  for (int j = 0; j < 4; ++j) {
    int tr = tb * 16 + lq * 4 + j;
    tk4[j] = (tr < nv) ? perm[start + tr] : -1;
  }
  // hoist all Bt loads (2 d-tiles x K=64)
  int d0 = dbase + l16, d1 = dbase + 16 + l16;
  const __bf16* br0 = Bt + (size_t)d0 * TOTR + a * RANK + lq * 8;
  const __bf16* br1 = Bt + (size_t)d1 * TOTR + a * RANK + lq * 8;
  bf16x8 b00 = *(const bf16x8*)(br0);
  bf16x8 b01 = *(const bf16x8*)(br0 + 32);
  bf16x8 b10 = *(const bf16x8*)(br1);
  bf16x8 b11 = *(const bf16x8*)(br1 + 32);
  // hoist base loads
  float bs[2][4];
#pragma unroll
  for (int j = 0; j < 4; ++j) {
    bs[0][j] = (tk4[j] >= 0) ? base[(size_t)tk4[j] * DOUT + d0] : 0.f;
    bs[1][j] = (tk4[j] >= 0) ? base[(size_t)tk4[j] * DOUT + d1] : 0.f;
  }
  f32x4 z0 = {0.f, 0.f, 0.f, 0.f}, z1 = {0.f, 0.f, 0.f, 0.f};
  z0 = __builtin_amdgcn_mfma_f32_16x16x32_bf16(af0, b00, z0, 0, 0, 0);
  z0 = __builtin_amdgcn_mfma_f32_16x16x32_bf16(af1, b01, z0, 0, 0, 0);
  z1 = __builtin_amdgcn_mfma_f32_16x16x32_bf16(af0, b10, z1, 0, 0, 0);
  z1 = __builtin_amdgcn_mfma_f32_16x16x32_bf16(af1, b11, z1, 0, 0, 0);
#pragma unroll
  for (int j = 0; j < 4; ++j) {
    if (tk4[j] >= 0) {
      size_t o0 = (size_t)tk4[j] * DOUT + d0;
      size_t o1 = (size_t)tk4[j] * DOUT + d1;
      out[o0] = bs[0][j] + 2.0f * z0[j];
      out[o1] = bs[1][j] + 2.0f * z1[j];
    }
  }
}

extern "C" void kernel_launch(void* const* d_in, const int* in_sizes, int n_in,
                              void* d_out, int out_size, void* d_ws, size_t ws_size,
                              hipStream_t stream) {
  const float* x   = (const float*)d_in[0];
  const float* A   = (const float*)d_in[1];
  const float* B   = (const float*)d_in[2];
  const float* bas = (const float*)d_in[3];
  const int*   ids = (const int*)d_in[4];
  float* out = (float*)d_out;
  char* ws = (char*)d_ws;
  int* cursors = (int*)(ws + WS_CURSORS);
  int* ntiles  = (int*)(ws + WS_NTILES);
  int* flag    = (int*)(ws + WS_FLAG);
  int* tinfo   = (int*)(ws + WS_TINFO);
  int* perm    = (int*)(ws + WS_PERM);
  __bf16* xa   = (__bf16*)(ws + WS_XA);
  __bf16* Abf  = (__bf16*)(ws + WS_ABF);
  __bf16* Bt   = (__bf16*)(ws + WS_BT);
  float*  xap  = (float*)(ws + WS_XAP);

  hist_prep<<<1, 1024, 0, stream>>>(ids, cursors, ntiles, flag, tinfo);
  scatter_k<<<T_TOK / 512, 512, 0, stream>>>(ids, flag, cursors, perm);
  conv_a<<<(TOTR * DIN / 4) / 256, 256, 0, stream>>>(A, Abf);
  trans_b<<<dim3(TOTR / 64, DOUT / 64), 256, 0, stream>>>(B, Bt);
  if (ws_size >= WS_END) {
    stage1s<<<dim3(MAXTILES, KSPLIT), 512, 0, stream>>>(x, Abf, tinfo, ntiles, perm, xap);
    reduce_xa<<<(T_TOK * RANK / 4) / 256, 256, 0, stream>>>(xap, xa);
  } else {
    stage1f<<<MAXTILES, 512, 0, stream>>>(x, Abf, tinfo, ntiles, perm, xa);
  }
  stage2<<<dim3(DOUT / 128, MAXTILES), 512, 0, stream>>>(xa, Bt, bas, tinfo, ntiles, perm, out);
}